// Round 2
// baseline (251.352 us; speedup 1.0000x reference)
//
#include <hip/hip_runtime.h>
#include <hip/hip_bf16.h>
#include <hip/hip_fp16.h>
#include <math.h>

#define BB 128
#define NN 12000
#define NIN 4000
#define NFN 7000
#define NOMIC 3600
#define FC 56000
#define EE 57000
#define LAT 100

typedef __hip_bfloat16 bf16;
typedef __attribute__((ext_vector_type(8))) short bf16x8;
typedef __attribute__((ext_vector_type(4))) float f32x4;

__device__ __forceinline__ ushort f2bf(float f) {
  bf16 h = __float2bfloat16(f);
  return *(ushort*)&h;
}
__device__ __forceinline__ float bf2f(ushort u) {
  bf16 h = *(bf16*)&u;
  return __bfloat162float(h);
}
__device__ __forceinline__ ushort f2h(float f) {
  __half h = __float2half(f);
  return *(ushort*)&h;
}
__device__ __forceinline__ float h2f(ushort u) {
  __half h = *(__half*)&u;
  return __half2float(h);
}
// fast elu for v<=0 path; __expf -> v_exp_f32 based, rel err ~1e-6 (noise vs bf16)
__device__ __forceinline__ float felu(float v) {
  return v > 0.f ? v : __expf(v) - 1.f;
}

// ---- prep0: transpose + zero(d_out) + map=-1 + zero(h_raw|red|needf) ----
// grid = 3243 x 256: [0,1500) transpose, [1500,3000) zero out,
// [3000,3223) map=-1, [3223,3243) zero h_raw+red+needf (5056 float4).
__global__ void k_prep0(const float* __restrict__ x, float* __restrict__ xT,
                        int* __restrict__ map, float* __restrict__ out,
                        float* __restrict__ wz) {
  int u = blockIdx.x;
  int tid = threadIdx.x;
  if (u < 1500) {
    __shared__ float t[32][33];
    int n0 = (u % 375) * 32, b0 = (u / 375) * 32;
    int tx = tid & 31, ty = tid >> 5;
#pragma unroll
    for (int s = 0; s < 4; s++)
      t[ty + s * 8][tx] = x[(b0 + ty + s * 8) * NN + n0 + tx];
    __syncthreads();
#pragma unroll
    for (int s = 0; s < 4; s++)
      xT[(n0 + ty + s * 8) * BB + b0 + tx] = t[tx][ty + s * 8];
  } else if (u < 3000) {
    int idx = (u - 1500) * 256 + tid;  // 384,000 float4 exactly
    ((float4*)out)[idx] = make_float4(0.f, 0.f, 0.f, 0.f);
  } else if (u < 3223) {
    int i = (u - 3000) * 256 + tid;
    if (i < EE) map[i] = -1;
  } else {
    int idx = (u - 3223) * 256 + tid;  // h_raw(12800)+red(256)+needf(7168i) = 5056 f4
    if (idx < 5056) ((float4*)wz)[idx] = make_float4(0.f, 0.f, 0.f, 0.f);
  }
}

// ---- mid: ae1 split-K + xeF/xeO build + map fill + needf fill ----
// grid = 5004 + nb_fe: [0,1000) ae1 (2 halves per block), [1000,4500) xeF,
// [4500,5000) xeO, [5000,5000+nb_fe) map fill, last 4 blocks needf fill.
__global__ void k_mid(const float* __restrict__ xT, const float* __restrict__ W1,
                      float* __restrict__ h, const int* __restrict__ src,
                      uint4* __restrict__ xeF, ushort* __restrict__ xeO,
                      const int* __restrict__ w3_cols, int* __restrict__ map,
                      int* __restrict__ needf, int n_fe) {
  int u = blockIdx.x;
  int tid = threadIdx.x;
  int nb_fe = (n_fe + 255) >> 8;
  if (u < 1000) {
    int half_id = u * 2 + (tid >> 7);
    int b = tid & 127;
    int j0 = (half_id % 25) * 4;
    int k0 = (half_id / 25) * 45;
    float acc0 = 0.f, acc1 = 0.f, acc2 = 0.f, acc3 = 0.f;
    const float* xp = &xT[(size_t)k0 * BB + b];
    const float* wp = &W1[(size_t)k0 * LAT + j0];
#pragma unroll 5
    for (int kk = 0; kk < 45; kk++) {
      float xv = xp[kk * BB];
      float4 w = *(const float4*)(wp + kk * LAT);
      acc0 += xv * w.x; acc1 += xv * w.y; acc2 += xv * w.z; acc3 += xv * w.w;
    }
    atomicAdd(&h[(j0 + 0) * BB + b], acc0);
    atomicAdd(&h[(j0 + 1) * BB + b], acc1);
    atomicAdd(&h[(j0 + 2) * BB + b], acc2);
    atomicAdd(&h[(j0 + 3) * BB + b], acc3);
  } else if (u < 4500) {
    int gid = (u - 1000) * 256 + tid;
    int f = gid >> 7, b = gid & 127;
    union { ushort uu[8]; uint4 v; } p;
#pragma unroll
    for (int c = 0; c < 8; c++) {
      int s = src[f * 8 + c];
      p.uu[c] = (s < NOMIC) ? (ushort)f2bf(0.f) : f2bf(xT[s * BB + b]);
    }
    xeF[(size_t)f * BB + b] = p.v;
  } else if (u < 5000) {
    int idx = (u - 4500) * 256 + tid;
    int eo = idx >> 7, b = idx & 127;
    int s = src[FC + eo];
    xeO[idx] = (s < NOMIC) ? (ushort)f2bf(0.f) : f2bf(xT[s * BB + b]);
  } else if (u < 5000 + nb_fe) {
    int i = (u - 5000) * 256 + tid;
    if (i < n_fe) map[w3_cols[i * 8]] = i;
  } else {
    int i = (u - (5000 + nb_fe)) * 256 + tid;
    if (i < 1000) {
      int s = src[FC + i];
      needf[s - NIN] = 1;
    }
  }
}

// ---- AE layer 2 GEMM via MFMA. W2 tile staged through LDS with coalesced
//      float4 loads (f32->bf16 in-kernel); [k][jl] tile, row stride 66 ushorts
//      (odd word stride -> conflict-free fragment column reads).
//      elu(h)+staging rebuilt per block in LDS. zT = z (bf16), + LN sums. ----
__launch_bounds__(256)
__global__ void k_ae2(const float* __restrict__ h, const float* __restrict__ b_ae1,
                      const float* __restrict__ W2, const float* __restrict__ b_ae2,
                      ushort* __restrict__ zT, float* __restrict__ red) {
  __shared__ __align__(16) ushort hB[16384];
  __shared__ __align__(8) ushort w2t[128 * 66];
  __shared__ float lred[256];
  int tid = threadIdx.x;
  lred[tid] = 0.f;
  // stage elu(h + b_ae1) in B-fragment order (same for every block)
#pragma unroll
  for (int r = 0; r < 8; r++) {
    int e = r * 256 + tid;  // fragment-entry index 0..2047
    int lane2 = e & 63, t2 = (e >> 6) & 7, S2 = e >> 9;
    int k0 = S2 * 32 + (lane2 >> 4) * 8;
    int b = t2 * 16 + (lane2 & 15);
    union { ushort uu[8]; uint4 v; } p;
#pragma unroll
    for (int i = 0; i < 8; i++) {
      int k = k0 + i;
      float v = 0.f;
      if (k < LAT) {
        v = h[k * BB + b] + b_ae1[k];
        v = felu(v);
      }
      p.uu[i] = f2bf(v);
    }
    *(uint4*)&hB[e * 8] = p.v;
  }
  // stage W2 tile: rows k=0..99 (100..127 zeroed), 64 cols, coalesced float4
  {
    int r0 = tid >> 4, cg = tid & 15;
    const float* wsrc = &W2[(size_t)blockIdx.x * 64 + cg * 4];
#pragma unroll
    for (int p2 = 0; p2 < 8; p2++) {
      int k = p2 * 16 + r0;
      uint w01 = 0, w23 = 0;
      if (k < LAT) {
        float4 w = *(const float4*)(wsrc + (size_t)k * FC);
        w01 = (uint)f2bf(w.x) | ((uint)f2bf(w.y) << 16);
        w23 = (uint)f2bf(w.z) | ((uint)f2bf(w.w) << 16);
      }
      *(uint*)&w2t[k * 66 + cg * 4] = w01;
      *(uint*)&w2t[k * 66 + cg * 4 + 2] = w23;
    }
  }
  __syncthreads();
  int wave = tid >> 6, lane = tid & 63;
  int J = blockIdx.x * 4 + wave;
  int j0 = J * 16;
  int q = lane >> 4, n = lane & 15;
  bf16x8 a[4];
#pragma unroll
  for (int S = 0; S < 4; S++) {
    int k0 = S * 32 + q * 8;
    int jl = wave * 16 + n;
    union { ushort uu[8]; bf16x8 v; } aa;
#pragma unroll
    for (int i = 0; i < 8; i++) aa.uu[i] = w2t[(k0 + i) * 66 + jl];
    a[S] = aa.v;
  }
  float4 bias = *(const float4*)&b_ae2[j0 + q * 4];
  int jb = j0 + q * 4;
  int f = jb >> 3, c0 = jb & 7;
#pragma unroll
  for (int t = 0; t < 8; t++) {
    f32x4 acc = (f32x4){0.f, 0.f, 0.f, 0.f};
#pragma unroll
    for (int S = 0; S < 4; S++) {
      bf16x8 bfr = *(const bf16x8*)&hB[((S * 8 + t) * 64 + lane) * 8];
      acc = __builtin_amdgcn_mfma_f32_16x16x32_bf16(a[S], bfr, acc, 0, 0, 0);
    }
    int b = t * 16 + n;
    float v0 = acc[0] + bias.x, v1 = acc[1] + bias.y;
    float v2 = acc[2] + bias.z, v3 = acc[3] + bias.w;
    ushort4 pk;
    pk.x = f2bf(v0); pk.y = f2bf(v1); pk.z = f2bf(v2); pk.w = f2bf(v3);
    *(ushort4*)&zT[(size_t)f * 1024 + b * 8 + c0] = pk;
    atomicAdd(&lred[b * 2], v0 + v1 + v2 + v3);
    atomicAdd(&lred[b * 2 + 1], v0 * v0 + v1 * v1 + v2 * v2 + v3 * v3);
  }
  __syncthreads();
  atomicAdd(&red[tid], lred[tid]);
}

// ---- layer1(0): hfc = elu(s * groupLN(8x8 matmul(xe) + b1));
//      also computes s = sigmoid(LN(z)) ONCE, stores fp16 in place over zT. ----
__launch_bounds__(256)
__global__ void k_layer1(const uint4* __restrict__ xeF, const float* __restrict__ w1l,
                         const float* __restrict__ b1l, uint4* __restrict__ zT4,
                         const float* __restrict__ red, uint4* __restrict__ hfcT4) {
  __shared__ __align__(16) float wsm[4][64];
  __shared__ float bsm[4][8];
  int tid = threadIdx.x;
  int fs = tid >> 6;
  int lane = tid & 63;
  int f = blockIdx.x * 4 + fs;
  wsm[tid >> 6][tid & 63] = w1l[blockIdx.x * 256 + tid];
  if (tid < 32) bsm[tid >> 3][tid & 7] = b1l[blockIdx.x * 32 + tid];
  __syncthreads();
#pragma unroll
  for (int half = 0; half < 2; half++) {
    int b = lane + half * 64;
    float mu_ln = red[b * 2] * (1.f / FC);
    float var_ln = red[b * 2 + 1] * (1.f / FC) - mu_ln * mu_ln;
    float isg_ln = rsqrtf(var_ln + 1e-5f);
    union { ushort u[8]; uint4 v; } xu;
    xu.v = xeF[(size_t)f * BB + b];
    float xv[8];
#pragma unroll
    for (int k = 0; k < 8; k++) xv[k] = bf2f(xu.u[k]);
    float acc[8];
#pragma unroll
    for (int c = 0; c < 8; c++) acc[c] = bsm[fs][c];
#pragma unroll
    for (int k = 0; k < 8; k++) {
      const float4* wp = (const float4*)&wsm[fs][k * 8];
      float4 w0 = wp[0], w1 = wp[1];
      acc[0] += xv[k] * w0.x; acc[1] += xv[k] * w0.y;
      acc[2] += xv[k] * w0.z; acc[3] += xv[k] * w0.w;
      acc[4] += xv[k] * w1.x; acc[5] += xv[k] * w1.y;
      acc[6] += xv[k] * w1.z; acc[7] += xv[k] * w1.w;
    }
    float mu = 0.f;
#pragma unroll
    for (int c = 0; c < 8; c++) mu += acc[c];
    mu *= 0.125f;
    float var = 0.f;
#pragma unroll
    for (int c = 0; c < 8; c++) { float d = acc[c] - mu; var += d * d; }
    var *= 0.125f;
    float sc = rsqrtf(var + 1e-5f);
    union { ushort u[8]; uint4 v; } zu;
    zu.v = zT4[(size_t)f * BB + b];
    union { ushort u[8]; uint4 v; } su;
    union { ushort u[8]; uint4 v; } pk;
#pragma unroll
    for (int c = 0; c < 8; c++) {
      float v = (acc[c] - mu) * sc;
      float zf = bf2f(zu.u[c]);
      float ex = __expf(-(zf - mu_ln) * isg_ln);
      float sv = __builtin_amdgcn_rcpf(1.f + ex);
      su.u[c] = f2h(sv);
      float hv = felu(sv * v);
      pk.u[c] = f2bf(hv);
    }
    zT4[(size_t)f * BB + b] = su.v;  // overwrite z with s (fp16), same thread
    hfcT4[(size_t)f * BB + b] = pk.v;
  }
}

// ---- fused layer2(l) + layer1(l+1). prune=1 (l=2): only blocks containing a
//      needed f (src of an out-edge) compute; no xeF store (xe[:FC] dead after). ----
__launch_bounds__(256)
__global__ void k_fused(const uint4* __restrict__ hfcIn, const float* __restrict__ w3l,
                        const float* __restrict__ b3l, const int* __restrict__ map,
                        const int* __restrict__ src, uint4* __restrict__ xeF,
                        ushort* __restrict__ xeO, const float* __restrict__ w1n,
                        const float* __restrict__ b1n, const uint4* __restrict__ sT4,
                        uint4* __restrict__ hfcOut, const int* __restrict__ needf,
                        int prune) {
  __shared__ float wsm3[16][8];
  __shared__ int gsm[16];
  __shared__ float bsm3[16];
  __shared__ __align__(16) float w1sm[2][64];
  __shared__ float b1sm[2][8];
  int tid = threadIdx.x;
  if (blockIdx.x < 3500) {
    int act0 = 1, act1 = 1;
    if (prune) {
      act0 = needf[blockIdx.x * 2];
      act1 = needf[blockIdx.x * 2 + 1];
      if ((act0 | act1) == 0) return;  // block-uniform, before any sync
    }
    int e0 = blockIdx.x * 16;
    if (tid < 128) {
      int q = tid >> 3, c = tid & 7;
      int ii = map[e0 + q];
      wsm3[q][c] = (ii >= 0) ? w3l[ii * 8 + c] : 0.f;
      w1sm[tid >> 6][tid & 63] = w1n[blockIdx.x * 128 + tid];
    } else if (tid < 144) {
      int q = tid - 128;
      gsm[q] = (map[e0 + q] >= 0) ? src[e0 + q] - NIN : -1;
    } else if (tid < 160) {
      int q = tid - 144;
      bsm3[q] = b3l[e0 + q];
    } else if (tid < 176) {
      int q = tid - 160;
      b1sm[q >> 3][q & 7] = b1n[blockIdx.x * 16 + q];
    }
    __syncthreads();
    int fs = tid >> 7, b = tid & 127;
    int f = blockIdx.x * 2 + fs;
    int act = fs ? act1 : act0;
    if (act) {
      union { ushort u[8]; uint4 v; } xe8;
      xe8.v = xeF[(size_t)f * BB + b];
      union { ushort u[8]; uint4 v; } pk;
      float xv[8];
#pragma unroll
      for (int c = 0; c < 8; c++) {
        int q = fs * 8 + c;
        int g = gsm[q];
        float rv = bf2f(xe8.u[c]) + bsm3[q];
        if (g >= 0) {
          union { ushort u[8]; uint4 v; } hv;
          hv.v = hfcIn[(size_t)g * BB + b];
          float a = 0.f;
#pragma unroll
          for (int j = 0; j < 8; j++) a += bf2f(hv.u[j]) * wsm3[q][j];
          rv += a;
        }
        pk.u[c] = f2bf(rv);
        xv[c] = bf2f(pk.u[c]);
      }
      if (!prune) xeF[(size_t)f * BB + b] = pk.v;
      // layer1(l+1) using s (fp16) — no LN-of-z recompute, no sigmoid
      float acc[8];
#pragma unroll
      for (int c = 0; c < 8; c++) acc[c] = b1sm[fs][c];
#pragma unroll
      for (int k = 0; k < 8; k++) {
        const float4* wp = (const float4*)&w1sm[fs][k * 8];
        float4 w0 = wp[0], w1 = wp[1];
        acc[0] += xv[k] * w0.x; acc[1] += xv[k] * w0.y;
        acc[2] += xv[k] * w0.z; acc[3] += xv[k] * w0.w;
        acc[4] += xv[k] * w1.x; acc[5] += xv[k] * w1.y;
        acc[6] += xv[k] * w1.z; acc[7] += xv[k] * w1.w;
      }
      float mu = 0.f;
#pragma unroll
      for (int c = 0; c < 8; c++) mu += acc[c];
      mu *= 0.125f;
      float var = 0.f;
#pragma unroll
      for (int c = 0; c < 8; c++) { float d = acc[c] - mu; var += d * d; }
      var *= 0.125f;
      float sc = rsqrtf(var + 1e-5f);
      union { ushort u[8]; uint4 v; } su;
      su.v = sT4[(size_t)f * BB + b];
      union { ushort u[8]; uint4 v; } hk;
#pragma unroll
      for (int c = 0; c < 8; c++) {
        float v = (acc[c] - mu) * sc;
        float hv = felu(h2f(su.u[c]) * v);
        hk.u[c] = f2bf(hv);
      }
      hfcOut[(size_t)f * BB + b] = hk.v;
    }
  } else {
    int e0 = FC + (blockIdx.x - 3500) * 4;
    if (tid < 32) {
      int q = tid;
      int ee = e0 + (q >> 3);
      int ii = map[ee];
      wsm3[q >> 3][q & 7] = (ii >= 0) ? w3l[ii * 8 + (q & 7)] : 0.f;
    }
    __syncthreads();
    int es = tid >> 6, lane = tid & 63;
    int e = e0 + es;
    int i = map[e];
    int g = src[e] - NIN;
    float be = b3l[e];
#pragma unroll
    for (int half = 0; half < 2; half++) {
      int b = lane + half * 64;
      float rv = be + bf2f(xeO[(e - FC) * BB + b]);
      if (i >= 0) {
        union { ushort u[8]; uint4 v; } hv;
        hv.v = hfcIn[(size_t)g * BB + b];
        float a = 0.f;
#pragma unroll
        for (int c = 0; c < 8; c++) a += bf2f(hv.u[c]) * wsm3[es][c];
        rv += a;
      }
      xeO[(e - FC) * BB + b] = f2bf(rv);
    }
  }
}

// ---- out: applies the l=3 out-edge update (only live part of layer 3) and
//      transposes: out[b, 11000+j] = (xeO[j][b] + b3[3] + w3[3]·hfc3[src]) / 4 ----
__global__ void k_out(const ushort* __restrict__ xeO, const uint4* __restrict__ hfc3,
                      const int* __restrict__ map, const int* __restrict__ src,
                      const float* __restrict__ w3l, const float* __restrict__ b3l,
                      float* __restrict__ out) {
  __shared__ float t[32][33];
  __shared__ float w3s[32][8];
  __shared__ float bs[32];
  __shared__ int gs[32];
  int j0 = blockIdx.x * 32, b0 = blockIdx.y * 32;
  int tx = threadIdx.x, ty = threadIdx.y;
  int tid = ty * 32 + tx;
  {
    int q = tid >> 3, c = tid & 7;
    int j = j0 + q;
    int ii = (j < 1000) ? map[FC + j] : -1;
    w3s[q][c] = (ii >= 0) ? w3l[ii * 8 + c] : 0.f;
  }
  if (tid < 32) {
    int j = j0 + tid;
    bs[tid] = (j < 1000) ? b3l[FC + j] : 0.f;
    gs[tid] = (j < 1000) ? src[FC + j] - NIN : -1;
  }
  __syncthreads();
#pragma unroll
  for (int s2 = 0; s2 < 4; s2++) {
    int jl = ty + s2 * 8;
    int j = j0 + jl;
    float rv = 0.f;
    if (j < 1000) {
      int b = b0 + tx;
      rv = bf2f(xeO[j * BB + b]) + bs[jl];
      int g = gs[jl];
      if (g >= 0) {
        union { ushort u[8]; uint4 v; } hv;
        hv.v = hfc3[(size_t)g * BB + b];
        float a = 0.f;
#pragma unroll
        for (int c = 0; c < 8; c++) a += bf2f(hv.u[c]) * w3s[jl][c];
        rv += a;
      }
    }
    t[jl][tx] = rv * 0.25f;
  }
  __syncthreads();
#pragma unroll
  for (int s2 = 0; s2 < 4; s2++) {
    int b = b0 + ty + s2 * 8;
    int j = j0 + tx;
    if (j < 1000) out[b * NN + 11000 + j] = t[tx][ty + s2 * 8];
  }
}

extern "C" void kernel_launch(void* const* d_in, const int* in_sizes, int n_in,
                              void* d_out, int out_size, void* d_ws, size_t ws_size,
                              hipStream_t stream) {
  const float* x = (const float*)d_in[0];
  const float* W_ae1 = (const float*)d_in[1];
  const float* b_ae1 = (const float*)d_in[2];
  const float* W2 = (const float*)d_in[3];
  const float* b_ae2 = (const float*)d_in[4];
  const float* w1_vals = (const float*)d_in[5];
  const float* b1 = (const float*)d_in[6];
  const float* w3_vals = (const float*)d_in[7];
  const float* b3 = (const float*)d_in[8];
  const int* src = (const int*)d_in[9];
  const int* w3_cols = (const int*)d_in[14];

  int nnz3 = in_sizes[13];
  int n_fe = nnz3 / 8;
  int nb_fe = (n_fe + 255) / 256;

  // Workspace (f32 slot offsets); all uint4 regions 16B-aligned.
  float* W = (float*)d_ws;
  float* h_raw = W + 0;                    // 12,800  [k*128+b]
  float* red = W + 12800;                  // 256
  int* needf = (int*)(W + 13056);          // 7,168 ints (pad) -> ends 20,224
  int* map = (int*)(W + 20224);            // 57,088 ints (pad) -> ends 77,312
  float* xT = W + 77312;                   // 1,536,000 -> ends 1,613,312
  uint4* xeF = (uint4*)(W + 1613312);      // 3,584,000 -> ends 5,197,312
  ushort* xeO = (ushort*)(W + 5197312);    // 64,000 -> ends 5,261,312
  uint4* zT4 = (uint4*)(W + 5261312);      // 3,584,000 -> ends 8,845,312 (z then s)
  uint4* hfcA = (uint4*)(W + 8845312);     // 3,584,000 -> ends 12,429,312
  uint4* hfcB = (uint4*)(W + 12429312);    // 3,584,000 -> ends 16,013,312

  k_prep0<<<3243, 256, 0, stream>>>(x, xT, map, (float*)d_out, W);
  k_mid<<<5004 + nb_fe, 256, 0, stream>>>(xT, W_ae1, h_raw, src, xeF, xeO, w3_cols,
                                          map, needf, n_fe);
  k_ae2<<<875, 256, 0, stream>>>(h_raw, b_ae1, W2, b_ae2, (ushort*)zT4, red);
  k_layer1<<<NFN / 4, 256, 0, stream>>>(xeF, w1_vals, b1, zT4, red, hfcA);
  uint4* hin = hfcA;
  uint4* hout = hfcB;
  for (int l = 0; l < 3; l++) {
    k_fused<<<3750, 256, 0, stream>>>(hin, w3_vals + (size_t)l * nnz3,
                                      b3 + (size_t)l * EE, map, src, xeF, xeO,
                                      w1_vals + (size_t)(l + 1) * 448000,
                                      b1 + (size_t)(l + 1) * FC, zT4, hout, needf,
                                      (l == 2) ? 1 : 0);
    uint4* tmp = hin; hin = hout; hout = tmp;
  }
  k_out<<<dim3(32, 4), dim3(32, 8), 0, stream>>>(xeO, hin, map, src,
                                                 w3_vals + (size_t)3 * nnz3,
                                                 b3 + (size_t)3 * EE, (float*)d_out);
}

// Round 3
// 234.515 us; speedup vs baseline: 1.0718x; 1.0718x over previous
//
#include <hip/hip_runtime.h>
#include <hip/hip_bf16.h>
#include <hip/hip_fp16.h>
#include <math.h>

#define BB 128
#define NN 12000
#define NIN 4000
#define NFN 7000
#define NOMIC 3600
#define FC 56000
#define EE 57000
#define LAT 100

typedef __hip_bfloat16 bf16;
typedef __attribute__((ext_vector_type(8))) short bf16x8;
typedef __attribute__((ext_vector_type(4))) float f32x4;

__device__ __forceinline__ ushort f2bf(float f) {
  bf16 h = __float2bfloat16(f);
  return *(ushort*)&h;
}
__device__ __forceinline__ float bf2f(ushort u) {
  bf16 h = *(bf16*)&u;
  return __bfloat162float(h);
}
__device__ __forceinline__ ushort f2h(float f) {
  __half h = __float2half(f);
  return *(ushort*)&h;
}
__device__ __forceinline__ float h2f(ushort u) {
  __half h = *(__half*)&u;
  return __half2float(h);
}
// fast elu for v<=0 path; __expf -> v_exp_f32 based, rel err ~1e-6 (noise vs bf16)
__device__ __forceinline__ float felu(float v) {
  return v > 0.f ? v : __expf(v) - 1.f;
}

// ---- prep0: transpose + zero(d_out) + map=-1 + zero(h_raw|red|needf) ----
// grid = 3243 x 256: [0,1500) transpose, [1500,3000) zero out,
// [3000,3223) map=-1, [3223,3243) zero h_raw+red+needf (5056 float4).
__global__ void k_prep0(const float* __restrict__ x, float* __restrict__ xT,
                        int* __restrict__ map, float* __restrict__ out,
                        float* __restrict__ wz) {
  int u = blockIdx.x;
  int tid = threadIdx.x;
  if (u < 1500) {
    __shared__ float t[32][33];
    int n0 = (u % 375) * 32, b0 = (u / 375) * 32;
    int tx = tid & 31, ty = tid >> 5;
#pragma unroll
    for (int s = 0; s < 4; s++)
      t[ty + s * 8][tx] = x[(b0 + ty + s * 8) * NN + n0 + tx];
    __syncthreads();
#pragma unroll
    for (int s = 0; s < 4; s++)
      xT[(n0 + ty + s * 8) * BB + b0 + tx] = t[tx][ty + s * 8];
  } else if (u < 3000) {
    int idx = (u - 1500) * 256 + tid;  // 384,000 float4 exactly
    ((float4*)out)[idx] = make_float4(0.f, 0.f, 0.f, 0.f);
  } else if (u < 3223) {
    int i = (u - 3000) * 256 + tid;
    if (i < EE) map[i] = -1;
  } else {
    int idx = (u - 3223) * 256 + tid;  // h_raw(12800)+red(256)+needf(7168i) = 5056 f4
    if (idx < 5056) ((float4*)wz)[idx] = make_float4(0.f, 0.f, 0.f, 0.f);
  }
}

// ---- mid: ae1 split-K + xeF/xeO build + map fill + needf fill ----
__global__ void k_mid(const float* __restrict__ xT, const float* __restrict__ W1,
                      float* __restrict__ h, const int* __restrict__ src,
                      uint4* __restrict__ xeF, ushort* __restrict__ xeO,
                      const int* __restrict__ w3_cols, int* __restrict__ map,
                      int* __restrict__ needf, int n_fe) {
  int u = blockIdx.x;
  int tid = threadIdx.x;
  int nb_fe = (n_fe + 255) >> 8;
  if (u < 1000) {
    int half_id = u * 2 + (tid >> 7);
    int b = tid & 127;
    int j0 = (half_id % 25) * 4;
    int k0 = (half_id / 25) * 45;
    float acc0 = 0.f, acc1 = 0.f, acc2 = 0.f, acc3 = 0.f;
    const float* xp = &xT[(size_t)k0 * BB + b];
    const float* wp = &W1[(size_t)k0 * LAT + j0];
#pragma unroll 5
    for (int kk = 0; kk < 45; kk++) {
      float xv = xp[kk * BB];
      float4 w = *(const float4*)(wp + kk * LAT);
      acc0 += xv * w.x; acc1 += xv * w.y; acc2 += xv * w.z; acc3 += xv * w.w;
    }
    atomicAdd(&h[(j0 + 0) * BB + b], acc0);
    atomicAdd(&h[(j0 + 1) * BB + b], acc1);
    atomicAdd(&h[(j0 + 2) * BB + b], acc2);
    atomicAdd(&h[(j0 + 3) * BB + b], acc3);
  } else if (u < 4500) {
    int gid = (u - 1000) * 256 + tid;
    int f = gid >> 7, b = gid & 127;
    union { ushort uu[8]; uint4 v; } p;
#pragma unroll
    for (int c = 0; c < 8; c++) {
      int s = src[f * 8 + c];
      p.uu[c] = (s < NOMIC) ? (ushort)f2bf(0.f) : f2bf(xT[s * BB + b]);
    }
    xeF[(size_t)f * BB + b] = p.v;
  } else if (u < 5000) {
    int idx = (u - 4500) * 256 + tid;
    int eo = idx >> 7, b = idx & 127;
    int s = src[FC + eo];
    xeO[idx] = (s < NOMIC) ? (ushort)f2bf(0.f) : f2bf(xT[s * BB + b]);
  } else if (u < 5000 + nb_fe) {
    int i = (u - 5000) * 256 + tid;
    if (i < n_fe) map[w3_cols[i * 8]] = i;
  } else {
    int i = (u - (5000 + nb_fe)) * 256 + tid;
    if (i < 1000) {
      int s = src[FC + i];
      needf[s - NIN] = 1;
    }
  }
}

// ---- hb: build hbf = elu(h + b_ae1) in MFMA B-fragment order, once. ----
// grid = 8 x 256; entry gid=(S*8+t)*64+lane holds 8 bf16: k=k0..k0+7, fixed b.
__global__ void k_hb(const float* __restrict__ h, const float* __restrict__ b_ae1,
                     ushort* __restrict__ hbf) {
  int gid = blockIdx.x * 256 + threadIdx.x;  // 0..2047
  int lane = gid & 63, t = (gid >> 6) & 7, S = gid >> 9;
  int k0 = S * 32 + (lane >> 4) * 8;
  int b = t * 16 + (lane & 15);
  union { ushort uu[8]; uint4 v; } p;
#pragma unroll
  for (int i = 0; i < 8; i++) {
    int k = k0 + i;
    float v = 0.f;
    if (k < LAT) {
      v = h[k * BB + b] + b_ae1[k];
      v = felu(v);
    }
    p.uu[i] = f2bf(v);
  }
  *(uint4*)&hbf[(size_t)gid * 8] = p.v;
}

// ---- AE layer 2 GEMM via MFMA. W2 tile: 8 float4 loads batched into regs
//      (max MLP), then bf16 convert -> LDS [k][jl] stride-66 (conflict-free).
//      B-fragments read directly from global hbf (L2-hot 32KB, coalesced).
//      LDS ~18KB -> occupancy VGPR-capped, not LDS-capped. ----
__launch_bounds__(256)
__global__ void k_ae2(const ushort* __restrict__ hbf, const float* __restrict__ W2,
                      const float* __restrict__ b_ae2, ushort* __restrict__ zT,
                      float* __restrict__ red) {
  __shared__ __align__(8) ushort w2t[128 * 66];
  __shared__ float lred[256];
  int tid = threadIdx.x;
  // stage W2 tile: batch all 8 strided float4 loads into registers first
  int r0 = tid >> 4, cg = tid & 15;
  const float* wsrc = &W2[(size_t)blockIdx.x * 64 + cg * 4];
  float4 wreg[8];
#pragma unroll
  for (int p2 = 0; p2 < 8; p2++) {
    int k = p2 * 16 + r0;
    wreg[p2] = (k < LAT) ? *(const float4*)(wsrc + (size_t)k * FC)
                         : make_float4(0.f, 0.f, 0.f, 0.f);
  }
  lred[tid] = 0.f;
#pragma unroll
  for (int p2 = 0; p2 < 8; p2++) {
    int k = p2 * 16 + r0;
    uint w01 = (uint)f2bf(wreg[p2].x) | ((uint)f2bf(wreg[p2].y) << 16);
    uint w23 = (uint)f2bf(wreg[p2].z) | ((uint)f2bf(wreg[p2].w) << 16);
    *(uint*)&w2t[k * 66 + cg * 4] = w01;
    *(uint*)&w2t[k * 66 + cg * 4 + 2] = w23;
  }
  __syncthreads();
  int wave = tid >> 6, lane = tid & 63;
  int J = blockIdx.x * 4 + wave;
  int j0 = J * 16;
  int q = lane >> 4, n = lane & 15;
  bf16x8 a[4];
#pragma unroll
  for (int S = 0; S < 4; S++) {
    int k0 = S * 32 + q * 8;
    int jl = wave * 16 + n;
    union { ushort uu[8]; bf16x8 v; } aa;
#pragma unroll
    for (int i = 0; i < 8; i++) aa.uu[i] = w2t[(k0 + i) * 66 + jl];
    a[S] = aa.v;
  }
  float4 bias = *(const float4*)&b_ae2[j0 + q * 4];
  int jb = j0 + q * 4;
  int f = jb >> 3, c0 = jb & 7;
#pragma unroll
  for (int t = 0; t < 8; t++) {
    f32x4 acc = (f32x4){0.f, 0.f, 0.f, 0.f};
#pragma unroll
    for (int S = 0; S < 4; S++) {
      bf16x8 bfr = *(const bf16x8*)&hbf[(size_t)(((S * 8 + t) * 64 + lane)) * 8];
      acc = __builtin_amdgcn_mfma_f32_16x16x32_bf16(a[S], bfr, acc, 0, 0, 0);
    }
    int b = t * 16 + n;
    float v0 = acc[0] + bias.x, v1 = acc[1] + bias.y;
    float v2 = acc[2] + bias.z, v3 = acc[3] + bias.w;
    ushort4 pk;
    pk.x = f2bf(v0); pk.y = f2bf(v1); pk.z = f2bf(v2); pk.w = f2bf(v3);
    *(ushort4*)&zT[(size_t)f * 1024 + b * 8 + c0] = pk;
    atomicAdd(&lred[b * 2], v0 + v1 + v2 + v3);
    atomicAdd(&lred[b * 2 + 1], v0 * v0 + v1 * v1 + v2 * v2 + v3 * v3);
  }
  __syncthreads();
  atomicAdd(&red[tid], lred[tid]);
}

// ---- layer1(0): hfc = elu(s * groupLN(8x8 matmul(xe) + b1));
//      also computes s = sigmoid(LN(z)) ONCE, stores fp16 in place over zT. ----
__launch_bounds__(256)
__global__ void k_layer1(const uint4* __restrict__ xeF, const float* __restrict__ w1l,
                         const float* __restrict__ b1l, uint4* __restrict__ zT4,
                         const float* __restrict__ red, uint4* __restrict__ hfcT4) {
  __shared__ __align__(16) float wsm[4][64];
  __shared__ float bsm[4][8];
  int tid = threadIdx.x;
  int fs = tid >> 6;
  int lane = tid & 63;
  int f = blockIdx.x * 4 + fs;
  wsm[tid >> 6][tid & 63] = w1l[blockIdx.x * 256 + tid];
  if (tid < 32) bsm[tid >> 3][tid & 7] = b1l[blockIdx.x * 32 + tid];
  __syncthreads();
#pragma unroll
  for (int half = 0; half < 2; half++) {
    int b = lane + half * 64;
    float mu_ln = red[b * 2] * (1.f / FC);
    float var_ln = red[b * 2 + 1] * (1.f / FC) - mu_ln * mu_ln;
    float isg_ln = rsqrtf(var_ln + 1e-5f);
    union { ushort u[8]; uint4 v; } xu;
    xu.v = xeF[(size_t)f * BB + b];
    float xv[8];
#pragma unroll
    for (int k = 0; k < 8; k++) xv[k] = bf2f(xu.u[k]);
    float acc[8];
#pragma unroll
    for (int c = 0; c < 8; c++) acc[c] = bsm[fs][c];
#pragma unroll
    for (int k = 0; k < 8; k++) {
      const float4* wp = (const float4*)&wsm[fs][k * 8];
      float4 w0 = wp[0], w1 = wp[1];
      acc[0] += xv[k] * w0.x; acc[1] += xv[k] * w0.y;
      acc[2] += xv[k] * w0.z; acc[3] += xv[k] * w0.w;
      acc[4] += xv[k] * w1.x; acc[5] += xv[k] * w1.y;
      acc[6] += xv[k] * w1.z; acc[7] += xv[k] * w1.w;
    }
    float mu = 0.f;
#pragma unroll
    for (int c = 0; c < 8; c++) mu += acc[c];
    mu *= 0.125f;
    float var = 0.f;
#pragma unroll
    for (int c = 0; c < 8; c++) { float d = acc[c] - mu; var += d * d; }
    var *= 0.125f;
    float sc = rsqrtf(var + 1e-5f);
    union { ushort u[8]; uint4 v; } zu;
    zu.v = zT4[(size_t)f * BB + b];
    union { ushort u[8]; uint4 v; } su;
    union { ushort u[8]; uint4 v; } pk;
#pragma unroll
    for (int c = 0; c < 8; c++) {
      float v = (acc[c] - mu) * sc;
      float zf = bf2f(zu.u[c]);
      float ex = __expf(-(zf - mu_ln) * isg_ln);
      float sv = __builtin_amdgcn_rcpf(1.f + ex);
      su.u[c] = f2h(sv);
      float hv = felu(sv * v);
      pk.u[c] = f2bf(hv);
    }
    zT4[(size_t)f * BB + b] = su.v;  // overwrite z with s (fp16), same thread
    hfcT4[(size_t)f * BB + b] = pk.v;
  }
}

// ---- fused layer2(l) + layer1(l+1). prune=1 (l=2): only blocks containing a
//      needed f (src of an out-edge) compute; no xeF store (xe[:FC] dead after). ----
__launch_bounds__(256)
__global__ void k_fused(const uint4* __restrict__ hfcIn, const float* __restrict__ w3l,
                        const float* __restrict__ b3l, const int* __restrict__ map,
                        const int* __restrict__ src, uint4* __restrict__ xeF,
                        ushort* __restrict__ xeO, const float* __restrict__ w1n,
                        const float* __restrict__ b1n, const uint4* __restrict__ sT4,
                        uint4* __restrict__ hfcOut, const int* __restrict__ needf,
                        int prune) {
  __shared__ float wsm3[16][8];
  __shared__ int gsm[16];
  __shared__ float bsm3[16];
  __shared__ __align__(16) float w1sm[2][64];
  __shared__ float b1sm[2][8];
  int tid = threadIdx.x;
  if (blockIdx.x < 3500) {
    int act0 = 1, act1 = 1;
    if (prune) {
      act0 = needf[blockIdx.x * 2];
      act1 = needf[blockIdx.x * 2 + 1];
      if ((act0 | act1) == 0) return;  // block-uniform, before any sync
    }
    int e0 = blockIdx.x * 16;
    if (tid < 128) {
      int q = tid >> 3, c = tid & 7;
      int ii = map[e0 + q];
      wsm3[q][c] = (ii >= 0) ? w3l[ii * 8 + c] : 0.f;
      w1sm[tid >> 6][tid & 63] = w1n[blockIdx.x * 128 + tid];
    } else if (tid < 144) {
      int q = tid - 128;
      gsm[q] = (map[e0 + q] >= 0) ? src[e0 + q] - NIN : -1;
    } else if (tid < 160) {
      int q = tid - 144;
      bsm3[q] = b3l[e0 + q];
    } else if (tid < 176) {
      int q = tid - 160;
      b1sm[q >> 3][q & 7] = b1n[blockIdx.x * 16 + q];
    }
    __syncthreads();
    int fs = tid >> 7, b = tid & 127;
    int f = blockIdx.x * 2 + fs;
    int act = fs ? act1 : act0;
    if (act) {
      union { ushort u[8]; uint4 v; } xe8;
      xe8.v = xeF[(size_t)f * BB + b];
      union { ushort u[8]; uint4 v; } pk;
      float xv[8];
#pragma unroll
      for (int c = 0; c < 8; c++) {
        int q = fs * 8 + c;
        int g = gsm[q];
        float rv = bf2f(xe8.u[c]) + bsm3[q];
        if (g >= 0) {
          union { ushort u[8]; uint4 v; } hv;
          hv.v = hfcIn[(size_t)g * BB + b];
          float a = 0.f;
#pragma unroll
          for (int j = 0; j < 8; j++) a += bf2f(hv.u[j]) * wsm3[q][j];
          rv += a;
        }
        pk.u[c] = f2bf(rv);
        xv[c] = bf2f(pk.u[c]);
      }
      if (!prune) xeF[(size_t)f * BB + b] = pk.v;
      // layer1(l+1) using s (fp16) — no LN-of-z recompute, no sigmoid
      float acc[8];
#pragma unroll
      for (int c = 0; c < 8; c++) acc[c] = b1sm[fs][c];
#pragma unroll
      for (int k = 0; k < 8; k++) {
        const float4* wp = (const float4*)&w1sm[fs][k * 8];
        float4 w0 = wp[0], w1 = wp[1];
        acc[0] += xv[k] * w0.x; acc[1] += xv[k] * w0.y;
        acc[2] += xv[k] * w0.z; acc[3] += xv[k] * w0.w;
        acc[4] += xv[k] * w1.x; acc[5] += xv[k] * w1.y;
        acc[6] += xv[k] * w1.z; acc[7] += xv[k] * w1.w;
      }
      float mu = 0.f;
#pragma unroll
      for (int c = 0; c < 8; c++) mu += acc[c];
      mu *= 0.125f;
      float var = 0.f;
#pragma unroll
      for (int c = 0; c < 8; c++) { float d = acc[c] - mu; var += d * d; }
      var *= 0.125f;
      float sc = rsqrtf(var + 1e-5f);
      union { ushort u[8]; uint4 v; } su;
      su.v = sT4[(size_t)f * BB + b];
      union { ushort u[8]; uint4 v; } hk;
#pragma unroll
      for (int c = 0; c < 8; c++) {
        float v = (acc[c] - mu) * sc;
        float hv = felu(h2f(su.u[c]) * v);
        hk.u[c] = f2bf(hv);
      }
      hfcOut[(size_t)f * BB + b] = hk.v;
    }
  } else {
    int e0 = FC + (blockIdx.x - 3500) * 4;
    if (tid < 32) {
      int q = tid;
      int ee = e0 + (q >> 3);
      int ii = map[ee];
      wsm3[q >> 3][q & 7] = (ii >= 0) ? w3l[ii * 8 + (q & 7)] : 0.f;
    }
    __syncthreads();
    int es = tid >> 6, lane = tid & 63;
    int e = e0 + es;
    int i = map[e];
    int g = src[e] - NIN;
    float be = b3l[e];
#pragma unroll
    for (int half = 0; half < 2; half++) {
      int b = lane + half * 64;
      float rv = be + bf2f(xeO[(e - FC) * BB + b]);
      if (i >= 0) {
        union { ushort u[8]; uint4 v; } hv;
        hv.v = hfcIn[(size_t)g * BB + b];
        float a = 0.f;
#pragma unroll
        for (int c = 0; c < 8; c++) a += bf2f(hv.u[c]) * wsm3[es][c];
        rv += a;
      }
      xeO[(e - FC) * BB + b] = f2bf(rv);
    }
  }
}

// ---- out: applies the l=3 out-edge update (only live part of layer 3) and
//      transposes: out[b, 11000+j] = (xeO[j][b] + b3[3] + w3[3]·hfc3[src]) / 4 ----
__global__ void k_out(const ushort* __restrict__ xeO, const uint4* __restrict__ hfc3,
                      const int* __restrict__ map, const int* __restrict__ src,
                      const float* __restrict__ w3l, const float* __restrict__ b3l,
                      float* __restrict__ out) {
  __shared__ float t[32][33];
  __shared__ float w3s[32][8];
  __shared__ float bs[32];
  __shared__ int gs[32];
  int j0 = blockIdx.x * 32, b0 = blockIdx.y * 32;
  int tx = threadIdx.x, ty = threadIdx.y;
  int tid = ty * 32 + tx;
  {
    int q = tid >> 3, c = tid & 7;
    int j = j0 + q;
    int ii = (j < 1000) ? map[FC + j] : -1;
    w3s[q][c] = (ii >= 0) ? w3l[ii * 8 + c] : 0.f;
  }
  if (tid < 32) {
    int j = j0 + tid;
    bs[tid] = (j < 1000) ? b3l[FC + j] : 0.f;
    gs[tid] = (j < 1000) ? src[FC + j] - NIN : -1;
  }
  __syncthreads();
#pragma unroll
  for (int s2 = 0; s2 < 4; s2++) {
    int jl = ty + s2 * 8;
    int j = j0 + jl;
    float rv = 0.f;
    if (j < 1000) {
      int b = b0 + tx;
      rv = bf2f(xeO[j * BB + b]) + bs[jl];
      int g = gs[jl];
      if (g >= 0) {
        union { ushort u[8]; uint4 v; } hv;
        hv.v = hfc3[(size_t)g * BB + b];
        float a = 0.f;
#pragma unroll
        for (int c = 0; c < 8; c++) a += bf2f(hv.u[c]) * w3s[jl][c];
        rv += a;
      }
    }
    t[jl][tx] = rv * 0.25f;
  }
  __syncthreads();
#pragma unroll
  for (int s2 = 0; s2 < 4; s2++) {
    int b = b0 + ty + s2 * 8;
    int j = j0 + tx;
    if (j < 1000) out[b * NN + 11000 + j] = t[tx][ty + s2 * 8];
  }
}

extern "C" void kernel_launch(void* const* d_in, const int* in_sizes, int n_in,
                              void* d_out, int out_size, void* d_ws, size_t ws_size,
                              hipStream_t stream) {
  const float* x = (const float*)d_in[0];
  const float* W_ae1 = (const float*)d_in[1];
  const float* b_ae1 = (const float*)d_in[2];
  const float* W2 = (const float*)d_in[3];
  const float* b_ae2 = (const float*)d_in[4];
  const float* w1_vals = (const float*)d_in[5];
  const float* b1 = (const float*)d_in[6];
  const float* w3_vals = (const float*)d_in[7];
  const float* b3 = (const float*)d_in[8];
  const int* src = (const int*)d_in[9];
  const int* w3_cols = (const int*)d_in[14];

  int nnz3 = in_sizes[13];
  int n_fe = nnz3 / 8;
  int nb_fe = (n_fe + 255) / 256;

  // Workspace (f32 slot offsets); all uint4 regions 16B-aligned.
  float* W = (float*)d_ws;
  float* h_raw = W + 0;                    // 12,800  [k*128+b]
  float* red = W + 12800;                  // 256
  int* needf = (int*)(W + 13056);          // 7,168 ints (pad) -> ends 20,224
  int* map = (int*)(W + 20224);            // 57,088 ints (pad) -> ends 77,312
  float* xT = W + 77312;                   // 1,536,000 -> ends 1,613,312
  uint4* xeF = (uint4*)(W + 1613312);      // 3,584,000 -> ends 5,197,312
  ushort* xeO = (ushort*)(W + 5197312);    // 64,000 -> ends 5,261,312
  uint4* zT4 = (uint4*)(W + 5261312);      // 3,584,000 -> ends 8,845,312 (z then s)
  uint4* hfcA = (uint4*)(W + 8845312);     // 3,584,000 -> ends 12,429,312
  uint4* hfcB = (uint4*)(W + 12429312);    // 3,584,000 -> ends 16,013,312
  ushort* hbf = (ushort*)(W + 16013312);   // 8,192 floats (16,384 bf16) -> 16,021,504

  k_prep0<<<3243, 256, 0, stream>>>(x, xT, map, (float*)d_out, W);
  k_mid<<<5004 + nb_fe, 256, 0, stream>>>(xT, W_ae1, h_raw, src, xeF, xeO, w3_cols,
                                          map, needf, n_fe);
  k_hb<<<8, 256, 0, stream>>>(h_raw, b_ae1, hbf);
  k_ae2<<<875, 256, 0, stream>>>(hbf, W2, b_ae2, (ushort*)zT4, red);
  k_layer1<<<NFN / 4, 256, 0, stream>>>(xeF, w1_vals, b1, zT4, red, hfcA);
  uint4* hin = hfcA;
  uint4* hout = hfcB;
  for (int l = 0; l < 3; l++) {
    k_fused<<<3750, 256, 0, stream>>>(hin, w3_vals + (size_t)l * nnz3,
                                      b3 + (size_t)l * EE, map, src, xeF, xeO,
                                      w1_vals + (size_t)(l + 1) * 448000,
                                      b1 + (size_t)(l + 1) * FC, zT4, hout, needf,
                                      (l == 2) ? 1 : 0);
    uint4* tmp = hin; hin = hout; hout = tmp;
  }
  k_out<<<dim3(32, 4), dim3(32, 8), 0, stream>>>(xeO, hin, map, src,
                                                 w3_vals + (size_t)3 * nnz3,
                                                 b3 + (size_t)3 * EE, (float*)d_out);
}